// Round 9
// baseline (133.425 us; speedup 1.0000x reference)
//
#include <hip/hip_runtime.h>
#include <hip/hip_bf16.h>

#ifndef __has_builtin
#define __has_builtin(x) 0
#endif

__device__ __forceinline__ float fast_exp2(float x) {
#if __has_builtin(__builtin_amdgcn_exp2f)
  return __builtin_amdgcn_exp2f(x);
#else
  return exp2f(x);
#endif
}
__device__ __forceinline__ float fast_rcp(float x) {
#if __has_builtin(__builtin_amdgcn_rcpf)
  return __builtin_amdgcn_rcpf(x);
#else
  return 1.0f / x;
#endif
}

constexpr int Bsz = 8, QL = 128, KL = 512, DD = 256, UU = 256;
constexpr int PR = 4;                    // rows per proj block (1280 blocks)
constexpr int DT = 8;                    // d-chunk in proj pipeline
constexpr int FQB = 2;                   // q rows per fused block
constexpr float NEG_INF = -1e6f;
constexpr float C2 = 2.885390081777927f; // 2*log2(e): exp2(C2*x) == exp(2x)

// ---------------------------------------------------------------------------
// Kernel 1: projections, pre-scaled by C2.
//   qp [b][q][u]  natural (coalesced store, lane = u)
//   kpT[b][u][k]  TRANSPOSED: scores lanes map to k, so the k-row must be
//                 contiguous. Stores are scattered (16B/lane @ 2KB stride) but
//                 fire-and-forget: ~16 MB line traffic, no stalls.
// PR=4 -> 1280 blocks (5/CU). Dual double-buffer: next tile's W AND rows
// issued before current tile's compute. Masked key blocks exit early.
// ---------------------------------------------------------------------------
__global__ __launch_bounds__(256) void proj_kernel(
    const float* __restrict__ query, const float* __restrict__ key,
    const float* __restrict__ Wq, const float* __restrict__ Wk,
    const int* __restrict__ valid_len,
    float* __restrict__ qp, float* __restrict__ kpT)
{
  const int u   = threadIdx.x;
  const int blk = blockIdx.x;
  constexpr int QBLKS = Bsz * QL / PR;   // 256
  const bool isQ = blk < QBLKS;
  const int  m0  = isQ ? blk * PR : (blk - QBLKS) * PR;

  int kb_ = 0, kk0 = 0;
  if (!isQ) {
    kb_ = m0 / KL; kk0 = m0 % KL;
    if (kk0 >= valid_len[kb_]) return;   // masked rows never read downstream
  }
  const float* __restrict__ in = isQ ? query : key;
  const float* __restrict__ W  = isQ ? Wq : Wk;
  const float* r0 = in + (size_t)m0 * DD;

  float acc[PR];
#pragma unroll
  for (int r = 0; r < PR; ++r) acc[r] = 0.f;

  float  w_c[DT], w_n[DT];
  float4 r_c[PR][2], r_n[PR][2];

#pragma unroll
  for (int j = 0; j < DT; ++j) w_c[j] = W[j * UU + u];
#pragma unroll
  for (int r = 0; r < PR; ++r) {
    r_c[r][0] = *reinterpret_cast<const float4*>(r0 + r * DD);
    r_c[r][1] = *reinterpret_cast<const float4*>(r0 + r * DD + 4);
  }

  for (int d = 0; d < DD; d += DT) {
    const int dn = (d + DT < DD) ? d + DT : 0;   // clamped dummy on last
#pragma unroll
    for (int j = 0; j < DT; ++j) w_n[j] = W[(dn + j) * UU + u];
#pragma unroll
    for (int r = 0; r < PR; ++r) {
      r_n[r][0] = *reinterpret_cast<const float4*>(r0 + r * DD + dn);
      r_n[r][1] = *reinterpret_cast<const float4*>(r0 + r * DD + dn + 4);
    }
#pragma unroll
    for (int r = 0; r < PR; ++r) {
      float a = acc[r];
      a = fmaf(r_c[r][0].x, w_c[0], a);
      a = fmaf(r_c[r][0].y, w_c[1], a);
      a = fmaf(r_c[r][0].z, w_c[2], a);
      a = fmaf(r_c[r][0].w, w_c[3], a);
      a = fmaf(r_c[r][1].x, w_c[4], a);
      a = fmaf(r_c[r][1].y, w_c[5], a);
      a = fmaf(r_c[r][1].z, w_c[6], a);
      a = fmaf(r_c[r][1].w, w_c[7], a);
      acc[r] = a;
    }
#pragma unroll
    for (int j = 0; j < DT; ++j) w_c[j] = w_n[j];
#pragma unroll
    for (int r = 0; r < PR; ++r) { r_c[r][0] = r_n[r][0]; r_c[r][1] = r_n[r][1]; }
  }

  if (isQ) {
    float* o = qp + (size_t)m0 * UU + u;
#pragma unroll
    for (int r = 0; r < PR; ++r) o[(size_t)r * UU] = acc[r] * C2;
  } else {
    float* o = kpT + ((size_t)kb_ * UU + u) * KL + kk0;
    *reinterpret_cast<float4*>(o) =
        make_float4(acc[0] * C2, acc[1] * C2, acc[2] * C2, acc[3] * C2);
  }
}

// ---------------------------------------------------------------------------
// Kernel 2: FUSED scores + masked softmax + PV for (b, 2 q-rows).
// 512 blocks (2/CU), 256 threads. Scores live in LDS; PV uses unnormalized
// exp weights, final scale by 1/sum.
//   Scores: wave w owns k-strip [128w,128w+128); lane l owns k = 128w+2l(+1)
//   x 2 q rows -> 4 accs, 8 trans per u. kpT[b][u][k]: lane reads ONE
//   coalesced float2 per u (8B/lane, 512B/wave), prefetched 8-u deep.
//   Fully-masked strips skip the u-loop and write NEG_INF.
//   Softmax: waves 0/1 reduce k-halves for both rows at once.
//   PV: thread = d; sps broadcast; value coalesced, 16-deep prefetch.
// ---------------------------------------------------------------------------
__global__ __launch_bounds__(256) void fused_attn_kernel(
    const float* __restrict__ value, const int* __restrict__ valid_len,
    const float* __restrict__ v_w, const float* __restrict__ qp,
    const float* __restrict__ kpT, float* __restrict__ out)
{
  __shared__ __align__(16) float2 sps[KL];   // 4 KB: scores -> exp weights
  __shared__ float2 qpq_s[UU];               // 2 KB: (q0,q1) per u
  __shared__ float  w2_s[UU];                // 1 KB
  __shared__ float2 red2[4];                 // [0,1]=max halves, [2,3]=sum halves

  const int t   = threadIdx.x;
  const int blk = blockIdx.x;
  const int b   = blk & 7;                   // batch fastest: mixed vlen per CU
  const int q0  = (blk >> 3) * FQB;
  const int vlen = valid_len[b];
  const int w = t >> 6, l = t & 63;

  // ---- stage qp rows (as float2 per u) + 2*v_w ----
  w2_s[t] = 2.0f * v_w[t];
  qpq_s[t] = make_float2(qp[(size_t)(b * QL + q0) * UU + t],
                         qp[(size_t)(b * QL + q0 + 1) * UU + t]);
  __syncthreads();

  // ---- scores for wave strip ----
  const int kb = 128 * w + 2 * l;            // lane's k pair base
  float a00 = 0.f, a01 = 0.f, a10 = 0.f, a11 = 0.f;  // [row][kslot]

  if (128 * w < vlen) {
    const float* __restrict__ kprow = kpT + (size_t)b * UU * KL + kb;
    float2 cur[8], nxt[8];
#pragma unroll
    for (int j = 0; j < 8; ++j)
      cur[j] = *reinterpret_cast<const float2*>(kprow + (size_t)j * KL);

    for (int u0 = 0; u0 < UU; u0 += 8) {
      const int un = (u0 + 8 < UU) ? u0 + 8 : 0;   // clamped dummy on last
#pragma unroll
      for (int j = 0; j < 8; ++j)
        nxt[j] = *reinterpret_cast<const float2*>(kprow + (size_t)(un + j) * KL);
#pragma unroll
      for (int j = 0; j < 8; ++j) {
        const float2 qv = qpq_s[u0 + j];     // ds_read_b64 broadcast
        const float  w2 = w2_s[u0 + j];
        const float2 kv = cur[j];
        const float e00 = fast_exp2(qv.x + kv.x);
        const float e01 = fast_exp2(qv.x + kv.y);
        const float e10 = fast_exp2(qv.y + kv.x);
        const float e11 = fast_exp2(qv.y + kv.y);
        a00 = fmaf(w2, fast_rcp(1.0f + e00), a00);
        a01 = fmaf(w2, fast_rcp(1.0f + e01), a01);
        a10 = fmaf(w2, fast_rcp(1.0f + e10), a10);
        a11 = fmaf(w2, fast_rcp(1.0f + e11), a11);
      }
#pragma unroll
      for (int j = 0; j < 8; ++j) cur[j] = nxt[j];
    }
  }
  // write scores (softmax shift-invariance: constant sum(v_w) dropped).
  // Lanes with k >= vlen may have computed on poison (masked kpT never
  // written) — discarded by the select here.
  {
    float4 sv;
    sv.x = (kb     < vlen) ? -a00 : NEG_INF;   // sps[kb].x   (row 0)
    sv.y = (kb     < vlen) ? -a10 : NEG_INF;   // sps[kb].y   (row 1)
    sv.z = (kb + 1 < vlen) ? -a01 : NEG_INF;   // sps[kb+1].x
    sv.w = (kb + 1 < vlen) ? -a11 : NEG_INF;   // sps[kb+1].y
    *reinterpret_cast<float4*>(&sps[kb]) = sv;
  }
  __syncthreads();

  // ---- softmax (both rows at once); waves 0,1 own k-halves ----
  float4 sa, sb;
  if (w < 2) {
    const int base = 256 * w + 4 * l;        // 4 consecutive k
    sa = *reinterpret_cast<const float4*>(&sps[base]);      // k, k+1
    sb = *reinterpret_cast<const float4*>(&sps[base + 2]);  // k+2, k+3
    float mx0 = fmaxf(fmaxf(sa.x, sa.z), fmaxf(sb.x, sb.z));
    float mx1 = fmaxf(fmaxf(sa.y, sa.w), fmaxf(sb.y, sb.w));
#pragma unroll
    for (int off = 32; off >= 1; off >>= 1) {
      mx0 = fmaxf(mx0, __shfl_xor(mx0, off, 64));
      mx1 = fmaxf(mx1, __shfl_xor(mx1, off, 64));
    }
    if (l == 0) red2[w] = make_float2(mx0, mx1);
  }
  __syncthreads();
  const float m0r = fmaxf(red2[0].x, red2[1].x);
  const float m1r = fmaxf(red2[0].y, red2[1].y);
  if (w < 2) {
    const int base = 256 * w + 4 * l;
    sa.x = __expf(sa.x - m0r);  sa.y = __expf(sa.y - m1r);
    sa.z = __expf(sa.z - m0r);  sa.w = __expf(sa.w - m1r);
    sb.x = __expf(sb.x - m0r);  sb.y = __expf(sb.y - m1r);
    sb.z = __expf(sb.z - m0r);  sb.w = __expf(sb.w - m1r);
    *reinterpret_cast<float4*>(&sps[base])     = sa;
    *reinterpret_cast<float4*>(&sps[base + 2]) = sb;
    float s0 = sa.x + sa.z + sb.x + sb.z;
    float s1 = sa.y + sa.w + sb.y + sb.w;
#pragma unroll
    for (int off = 32; off >= 1; off >>= 1) {
      s0 += __shfl_xor(s0, off, 64);
      s1 += __shfl_xor(s1, off, 64);
    }
    if (l == 0) red2[2 + w] = make_float2(s0, s1);
  }
  __syncthreads();
  const float inv0 = fast_rcp(red2[2].x + red2[3].x);  // sums >= 1
  const float inv1 = fast_rcp(red2[2].y + red2[3].y);

  // ---- PV: thread = d; unnormalized weights, scale at the end ----
  const float* __restrict__ vb = value + (size_t)b * KL * DD + t;
  float o0 = 0.f, o1 = 0.f;
  const int kmax = (vlen + 15) & ~15;        // sps beyond vlen is exactly 0

  float vc[16], vn[16];
#pragma unroll
  for (int j = 0; j < 16; ++j) vc[j] = vb[(size_t)j * DD];
  for (int k = 0; k < kmax; k += 16) {
    const int kn = (k + 16 < kmax) ? k + 16 : 0;
#pragma unroll
    for (int j = 0; j < 16; ++j) vn[j] = vb[(size_t)(kn + j) * DD];
#pragma unroll
    for (int j = 0; j < 16; ++j) {
      const float2 p = sps[k + j];           // broadcast
      o0 = fmaf(p.x, vc[j], o0);
      o1 = fmaf(p.y, vc[j], o1);
    }
#pragma unroll
    for (int j = 0; j < 16; ++j) vc[j] = vn[j];
  }
  out[(size_t)(b * QL + q0) * DD + t]     = o0 * inv0;
  out[(size_t)(b * QL + q0 + 1) * DD + t] = o1 * inv1;
}

extern "C" void kernel_launch(void* const* d_in, const int* in_sizes, int n_in,
                              void* d_out, int out_size, void* d_ws, size_t ws_size,
                              hipStream_t stream) {
  const float* query     = (const float*)d_in[0];
  const float* key       = (const float*)d_in[1];
  const float* value     = (const float*)d_in[2];
  const int*   valid_len = (const int*)d_in[3];
  const float* Wq        = (const float*)d_in[4];
  const float* Wk        = (const float*)d_in[5];
  const float* v_w       = (const float*)d_in[6];
  float* out = (float*)d_out;

  float* qp  = (float*)d_ws;                        // B*QL*U floats (1 MB)
  float* kpT = qp + (size_t)Bsz * QL * UU;          // B*U*KL floats (4 MB)

  const int proj_blocks = (Bsz * QL + Bsz * KL) / PR;   // 1280
  proj_kernel<<<proj_blocks, 256, 0, stream>>>(query, key, Wq, Wk, valid_len,
                                               qp, kpT);

  const int fused_blocks = Bsz * (QL / FQB);            // 512
  fused_attn_kernel<<<fused_blocks, 256, 0, stream>>>(value, valid_len, v_w,
                                                      qp, kpT, out);
}